// Round 6
// baseline (602.652 us; speedup 1.0000x reference)
//
#include <hip/hip_runtime.h>
#include <hip/hip_bf16.h>

// Problem constants (from reference setup_inputs)
#define F_SIZE 1024
#define E_DIM  128
#define N_D    6000
#define N_SE   1000
#define N_TOT  7000
#define M_TPL  300000
#define LAMB   1e-6f
#define KPAD   7040   // N_TOT rounded up (xT leading dim)
#define ALDA   7008   // Abf leading dim (7000 rounded to 8; 16B-aligned rows)
#define SPL_AX  16    // split-K for A@x: 110 x-tiles * 16 = 1760 blocks
#define SPL_MLP 12    // split-K for MLP1: 94 * 12 = 1128 blocks
#define SVPAD  7168   // svec row stride

typedef __bf16 bf16x8 __attribute__((ext_vector_type(8)));
typedef float  f32x4  __attribute__((ext_vector_type(4)));
typedef unsigned short u16;

__device__ __forceinline__ float hshrink(float v) {
    return fabsf(v) > LAMB ? v : 0.0f;
}

// RNE float -> bf16 bits (inputs are finite; no NaN handling needed)
__device__ __forceinline__ u16 f2bf(float f) {
    unsigned int u = __builtin_bit_cast(unsigned int, f);
    unsigned int r = u + 0x7fffu + ((u >> 16) & 1u);
    return (u16)(r >> 16);
}

// ---------------------------------------------------------------------------
// Contiguous streaming fp32 -> bf16 conversion with zero-padded row tail.
// One block per row; threads stride over 8-col chunks. src [M][K] fp32,
// dst [M][ldp] bf16 (cols in [K, ldp) zeroed -- poison-safe for the GEMM).
// This pass is a perfect stream: it runs at HBM rate, unlike the GEMM's
// 128B-granular strided pattern, and leaves dst L3-resident.
// ---------------------------------------------------------------------------
__global__ __launch_bounds__(256) void conv_pad_bf16(const float* __restrict__ src,
                                                     u16* __restrict__ dst,
                                                     int K, int ldp) {
    const int r = blockIdx.x;
    const int chunks = ldp >> 3;
    const float* sp = src + (size_t)r * K;
    u16* dp = dst + (size_t)r * ldp;
    for (int c8 = threadIdx.x; c8 < chunks; c8 += 256) {
        const int c = c8 * 8;
        u16 us[8];
        if (c + 8 <= K) {
            float4 v0 = *(const float4*)(sp + c);
            float4 v1 = *(const float4*)(sp + c + 4);
            us[0] = f2bf(v0.x); us[1] = f2bf(v0.y);
            us[2] = f2bf(v0.z); us[3] = f2bf(v0.w);
            us[4] = f2bf(v1.x); us[5] = f2bf(v1.y);
            us[6] = f2bf(v1.z); us[7] = f2bf(v1.w);
        } else {
#pragma unroll
            for (int i = 0; i < 8; i++)
                us[i] = (c + i < K) ? f2bf(sp[c + i]) : (u16)0;
        }
        *(uint4*)(dp + c) = *(uint4*)us;
    }
}

// ---------------------------------------------------------------------------
// Barrier-free streaming MFMA GEMM, split-K, bf16 A (pre-converted):
//   Cpart[sp][row][n] = sum_{k chunk} A[row][k] * BT[n][k]
// A bf16 [M][lda] (zero-padded cols), BT bf16 [128][ldbt] (zero-padded cols).
// Loads feed MFMA operands directly: per k-tile 6x16B loads + 8 MFMA, no VALU
// conversion. Register ping-pong prefetches tile t+1 during tile t's MFMAs.
// All K-tiles are uniform (pads are zeroed on both operands).
// ---------------------------------------------------------------------------
#define LOADT(AV, BV, kof)                                                    \
    {                                                                         \
        _Pragma("unroll") for (int mi = 0; mi < 2; mi++)                      \
            AV[mi] = *(const bf16x8*)(aP[mi] + (kof));                        \
        _Pragma("unroll") for (int ni = 0; ni < 4; ni++)                      \
            BV[ni] = *(const bf16x8*)(bP[ni] + (kof));                        \
    }

#define COMPUTE_T(AV, BV)                                                     \
    {                                                                         \
        _Pragma("unroll") for (int mi = 0; mi < 2; mi++)                      \
            _Pragma("unroll") for (int ni = 0; ni < 4; ni++)                  \
                acc[mi][ni] = __builtin_amdgcn_mfma_f32_16x16x32_bf16(        \
                    AV[mi], BV[ni], acc[mi][ni], 0, 0, 0);                    \
    }

__global__ __launch_bounds__(256) void gemm_direct_bf(const u16* __restrict__ A, int lda,
                                                      const u16* __restrict__ BT, int ldbt,
                                                      float* __restrict__ Cpart,
                                                      int M, int K) {
    const int tid  = threadIdx.x;
    const int lane = tid & 63;
    const int w    = tid >> 6;
    const int fm   = lane & 15;
    const int quad = lane >> 4;
    const int wm   = (w & 1) * 32;
    const int wn   = (w >> 1) * 64;
    const int row0 = blockIdx.x * 64;
    const int sp = blockIdx.y, nsp = gridDim.y;
    const int KT  = (K + 31) / 32;
    const int kt0 = sp * KT / nsp;
    const int kt1 = (sp + 1) * KT / nsp;

    // A: lane reads 8 consecutive bf16 of row (wm+mi*16+fm) at k = quad*8.
    const u16* aP[2];
#pragma unroll
    for (int mi = 0; mi < 2; mi++) {
        int r = row0 + wm + mi * 16 + fm;
        if (r > M - 1) r = M - 1;            // clamped rows never stored
        aP[mi] = A + (size_t)r * lda + quad * 8;
    }
    // B: lane reads 8 consecutive bf16 of row (wn+ni*16+fm) at k = quad*8.
    const u16* bP[4];
#pragma unroll
    for (int ni = 0; ni < 4; ni++) {
        int n = wn + ni * 16 + fm;
        bP[ni] = BT + (size_t)n * ldbt + quad * 8;
    }

    const f32x4 zero = {0.f, 0.f, 0.f, 0.f};
    f32x4 acc[2][4];
#pragma unroll
    for (int i = 0; i < 2; i++)
#pragma unroll
        for (int j = 0; j < 4; j++) acc[i][j] = zero;

    if (kt1 > kt0) {
        bf16x8 cA[2], cB[4], nA[2], nB[4];
        LOADT(cA, cB, kt0 * 32);
#pragma unroll 2
        for (int t = kt0 + 1; t < kt1; t++) {
            LOADT(nA, nB, t * 32);            // issue next tile's loads
            COMPUTE_T(cA, cB);                // MFMA current
#pragma unroll
            for (int mi = 0; mi < 2; mi++) cA[mi] = nA[mi];
#pragma unroll
            for (int ni = 0; ni < 4; ni++) cB[ni] = nB[ni];
        }
        COMPUTE_T(cA, cB);
    }

    float* op = Cpart + (size_t)sp * M * E_DIM;
#pragma unroll
    for (int mi = 0; mi < 2; mi++) {
#pragma unroll
        for (int rr = 0; rr < 4; rr++) {
            int row = row0 + wm + mi * 16 + quad * 4 + rr;
            if (row < M) {
#pragma unroll
                for (int ni = 0; ni < 4; ni++)
                    op[(size_t)row * E_DIM + wn + ni * 16 + fm] = acc[mi][ni][rr];
            }
        }
    }
}

// ---------------------------------------------------------------------------
// Small GEMM (K=128), BM=16: fuses the split-K reduction of its fp32 A input.
// ---------------------------------------------------------------------------
__global__ __launch_bounds__(256) void gemm_small2(const float* __restrict__ parts,
                                                   int nparts, size_t partStride,
                                                   const float* __restrict__ preBias,
                                                   const float* __restrict__ W,
                                                   const float* __restrict__ bias,
                                                   float* __restrict__ outp,
                                                   int Mrows, int act) {
    __shared__ float Asum[16][132];
    const int tid = threadIdx.x;
    const int row0 = blockIdx.x * 16;
    const int r  = tid >> 4;
    const int kc = (tid & 15) * 8;
    const int grow = row0 + r;

    float4 s0 = make_float4(0.f, 0.f, 0.f, 0.f);
    float4 s1 = make_float4(0.f, 0.f, 0.f, 0.f);
    if (grow < Mrows) {
        for (int s = 0; s < nparts; s++) {
            const float* p = parts + (size_t)s * partStride + (size_t)grow * 128 + kc;
            float4 q0 = *(const float4*)p;
            float4 q1 = *(const float4*)(p + 4);
            s0.x += q0.x; s0.y += q0.y; s0.z += q0.z; s0.w += q0.w;
            s1.x += q1.x; s1.y += q1.y; s1.z += q1.z; s1.w += q1.w;
        }
        if (preBias != nullptr) {
            float4 pb0 = *(const float4*)(preBias + kc);
            float4 pb1 = *(const float4*)(preBias + kc + 4);
            s0.x = fmaxf(s0.x + pb0.x, 0.f); s0.y = fmaxf(s0.y + pb0.y, 0.f);
            s0.z = fmaxf(s0.z + pb0.z, 0.f); s0.w = fmaxf(s0.w + pb0.w, 0.f);
            s1.x = fmaxf(s1.x + pb1.x, 0.f); s1.y = fmaxf(s1.y + pb1.y, 0.f);
            s1.z = fmaxf(s1.z + pb1.z, 0.f); s1.w = fmaxf(s1.w + pb1.w, 0.f);
        }
    }
    *(float4*)&Asum[r][kc]     = s0;
    *(float4*)&Asum[r][kc + 4] = s1;
    __syncthreads();

    float acc[8];
#pragma unroll
    for (int j = 0; j < 8; j++) acc[j] = 0.f;
    const float* wp = W + kc;
#pragma unroll 4
    for (int k = 0; k < 128; k++) {
        float a = Asum[r][k];
        float4 w0 = *(const float4*)(wp + (size_t)k * 128);
        float4 w1 = *(const float4*)(wp + (size_t)k * 128 + 4);
        acc[0] += a * w0.x; acc[1] += a * w0.y;
        acc[2] += a * w0.z; acc[3] += a * w0.w;
        acc[4] += a * w1.x; acc[5] += a * w1.y;
        acc[6] += a * w1.z; acc[7] += a * w1.w;
    }
    if (grow < Mrows) {
        float4 bv0 = *(const float4*)(bias + kc);
        float4 bv1 = *(const float4*)(bias + kc + 4);
        float v[8];
        v[0] = acc[0] + bv0.x; v[1] = acc[1] + bv0.y;
        v[2] = acc[2] + bv0.z; v[3] = acc[3] + bv0.w;
        v[4] = acc[4] + bv1.x; v[5] = acc[5] + bv1.y;
        v[6] = acc[6] + bv1.z; v[7] = acc[7] + bv1.w;
#pragma unroll
        for (int j = 0; j < 8; j++)
            v[j] = (act == 0) ? fmaxf(v[j], 0.f) : hshrink(v[j]);
        float* op = outp + (size_t)grow * 128 + kc;
        *(float4*)op       = make_float4(v[0], v[1], v[2], v[3]);
        *(float4*)(op + 4) = make_float4(v[4], v[5], v[6], v[7]);
    }
}

// ---------------------------------------------------------------------------
__global__ void emb_copy(const float* __restrict__ embSe, float* __restrict__ x) {
    int i = blockIdx.x * blockDim.x + threadIdx.x;
    if (i < N_SE * E_DIM / 4)
        ((float4*)(x + (size_t)N_D * E_DIM))[i] = ((const float4*)embSe)[i];
}

// ---------------------------------------------------------------------------
// src [nrows][128] fp32 -> dst [128][kpad] bf16 (cols >= nrows zero-filled)
// grid: (kpad/64, 2)
// ---------------------------------------------------------------------------
__global__ __launch_bounds__(256) void transpose_bf16(const float* __restrict__ src,
                                                      u16* __restrict__ dst,
                                                      int nrows, int kpad) {
    __shared__ float t[64][65];
    const int r0 = blockIdx.x * 64;
    const int c0 = blockIdx.y * 64;
    const int tid = threadIdx.x;
    {
        const int i  = tid >> 4;          // 0..15
        const int cq = (tid & 15) * 4;
#pragma unroll
        for (int j = 0; j < 4; j++) {
            int r = r0 + i + j * 16;
            float4 v = make_float4(0.f, 0.f, 0.f, 0.f);
            if (r < nrows) v = *(const float4*)(src + (size_t)r * E_DIM + c0 + cq);
            t[i + j * 16][cq + 0] = v.x;
            t[i + j * 16][cq + 1] = v.y;
            t[i + j * 16][cq + 2] = v.z;
            t[i + j * 16][cq + 3] = v.w;
        }
    }
    __syncthreads();
    {
        const int ci = tid >> 2;          // 0..63
        const int rq = (tid & 3) * 16;
        u16 us[16];
#pragma unroll
        for (int j = 0; j < 16; j++) us[j] = f2bf(t[rq + j][ci]);
        u16* dp = dst + (size_t)(c0 + ci) * kpad + r0 + rq;
        *(uint4*)dp       = *(uint4*)&us[0];
        *(uint4*)(dp + 8) = *(uint4*)&us[8];
    }
}

// ---------------------------------------------------------------------------
// Head algebra (inner hardshrink ~= identity at lambda=1e-6; induced error
// ~1e-8 << bf16 path error already accepted):
//   out[m] = HS( s0[d1] + s1[d2] + s2[se] + c0 )
//   s_j[r] = rsd[r] * sum_k x[r][k] * wv_j[k]
//   wv_j[k] = sum_n Wp1[j*128+k][n] * Wp2[n],  c0 = bp1.Wp2 + bp2
// ---------------------------------------------------------------------------
__global__ __launch_bounds__(256) void head_wvec(const float* __restrict__ Wp1,
                                                 const float* __restrict__ Wp2,
                                                 const float* __restrict__ bp1,
                                                 const float* __restrict__ bp2,
                                                 float* __restrict__ wv) {
    const int tid = threadIdx.x;
#pragma unroll
    for (int rr = 0; rr < 2; rr++) {
        int row = tid + rr * 256;
        if (row < 384) {
            const float* wp = Wp1 + (size_t)row * 128;
            float s = 0.f;
            for (int n = 0; n < 128; n += 4) {
                float4 a = *(const float4*)(wp + n);
                float4 b = *(const float4*)(Wp2 + n);
                s += a.x * b.x + a.y * b.y + a.z * b.z + a.w * b.w;
            }
            wv[row] = s;
        }
    }
    if (tid == 0) {
        float s = 0.f;
        for (int n = 0; n < 128; n++) s += bp1[n] * Wp2[n];
        wv[384] = s + bp2[0];
    }
}

// 64 rows/block, 4 lanes/row (32 cols each). svec[j*SVPAD + r].
__global__ __launch_bounds__(256) void head_svec(const float* __restrict__ x,
                                                 const float* __restrict__ rsd,
                                                 const float* __restrict__ wv,
                                                 float* __restrict__ svec) {
    __shared__ float wvL[384];
    const int tid = threadIdx.x;
    if (tid < 128) {
        wvL[tid]       = wv[tid];
        wvL[tid + 128] = wv[tid + 128];
        wvL[tid + 256] = wv[tid + 256];
    }
    __syncthreads();
    const int sub = tid & 3;
    const int r = blockIdx.x * 64 + (tid >> 2);
    if (r >= N_TOT) return;
    const float* xp = x + (size_t)r * E_DIM + sub * 32;
    float xr[32];
#pragma unroll
    for (int i = 0; i < 8; i++) {
        float4 v = *(const float4*)(xp + i * 4);
        xr[i * 4 + 0] = v.x; xr[i * 4 + 1] = v.y;
        xr[i * 4 + 2] = v.z; xr[i * 4 + 3] = v.w;
    }
    const float sc = rsd[r];
#pragma unroll
    for (int j = 0; j < 3; j++) {
        const float* wp = &wvL[j * 128 + sub * 32];
        float p = 0.f;
#pragma unroll
        for (int i = 0; i < 32; i++) p += xr[i] * wp[i];
        p += __shfl_xor(p, 1, 64);
        p += __shfl_xor(p, 2, 64);
        if (sub == 0) svec[j * SVPAD + r] = sc * p;
    }
}

// One thread per triple: 3 gathers from the 28 KB-per-segment svec tables.
__global__ __launch_bounds__(256) void head_final(const float* __restrict__ svec,
                                                  const int* __restrict__ tpl,
                                                  const float* __restrict__ wv,
                                                  float* __restrict__ outp) {
    int m = blockIdx.x * 256 + threadIdx.x;
    if (m >= M_TPL) return;
    int d1 = tpl[3 * m + 0];
    int d2 = tpl[3 * m + 1];
    int se = tpl[3 * m + 2];
    float c0 = wv[384];
    outp[m] = hshrink(svec[d1] + svec[SVPAD + d2] + svec[2 * SVPAD + se] + c0);
}

// ---------------------------------------------------------------------------
extern "C" void kernel_launch(void* const* d_in, const int* in_sizes, int n_in,
                              void* d_out, int out_size, void* d_ws, size_t ws_size,
                              hipStream_t stream) {
    const float* drugF = (const float*)d_in[0];
    const float* A     = (const float*)d_in[1];
    const int*   tpl   = (const int*)d_in[2];
    const float* rsd   = (const float*)d_in[3];
    const float* W1    = (const float*)d_in[4];
    const float* b1    = (const float*)d_in[5];
    const float* W2    = (const float*)d_in[6];
    const float* b2    = (const float*)d_in[7];
    const float* embSe = (const float*)d_in[8];
    const float* Wl    = (const float*)d_in[9];
    const float* bl    = (const float*)d_in[10];
    const float* Wp1   = (const float*)d_in[11];
    const float* bp1   = (const float*)d_in[12];
    const float* Wp2   = (const float*)d_in[13];
    const float* bp2   = (const float*)d_in[14];
    float* outp = (float*)d_out;

    float* ws = (float*)d_ws;
    const size_t XSZ = (size_t)N_TOT * E_DIM;   // 896000 floats
    const size_t P_AX  = (size_t)SPL_AX * XSZ;
    const size_t P_MLP = (size_t)SPL_MLP * N_D * E_DIM;
    const size_t PARTS = P_AX > P_MLP ? P_AX : P_MLP;
    float* x     = ws;
    float* parts = ws + XSZ;
    u16* xT   = (u16*)(ws + XSZ + PARTS);
    u16* W1T  = xT + (size_t)128 * KPAD;
    float* wv   = (float*)(W1T + (size_t)128 * 1024);   // 385 floats (pad 512)
    float* svec = wv + 512;                              // 3 * SVPAD floats
    u16* Abf  = (u16*)(svec + 3 * SVPAD);                // 7000 x ALDA bf16
    u16* dFbf = Abf + (size_t)N_TOT * ALDA;              // 6000 x 1024 bf16

    // 0) weight conversions + head weight-vector precompute + A/drugF -> bf16
    transpose_bf16<<<dim3(1024 / 64, 2), 256, 0, stream>>>(W1, W1T, F_SIZE, 1024);
    head_wvec<<<dim3(1), 256, 0, stream>>>(Wp1, Wp2, bp1, bp2, wv);
    conv_pad_bf16<<<dim3(N_TOT), 256, 0, stream>>>(A, Abf, N_TOT, ALDA);
    conv_pad_bf16<<<dim3(N_D), 256, 0, stream>>>(drugF, dFbf, F_SIZE, 1024);
    // 1) MLP layer 1 (streaming split-K, bf16 A) + fused-reduce layer 2
    gemm_direct_bf<<<dim3((N_D + 63) / 64, SPL_MLP), 256, 0, stream>>>(
        dFbf, 1024, W1T, 1024, parts, N_D, F_SIZE);
    gemm_small2<<<dim3((N_D + 15) / 16), 256, 0, stream>>>(
        parts, SPL_MLP, (size_t)N_D * E_DIM, b1, W2, b2, x, N_D, 0);
    // 2) embSe rows
    emb_copy<<<dim3((N_SE * E_DIM / 4 + 255) / 256), 256, 0, stream>>>(embSe, x);
    // 3) two propagation layers: x = HS( (A@x) @ Wl[i] + bl[i] )
    //    Abf (98 MB) is L3-resident from the conversion pass.
    for (int l = 0; l < 2; l++) {
        transpose_bf16<<<dim3(KPAD / 64, 2), 256, 0, stream>>>(x, xT, N_TOT, KPAD);
        gemm_direct_bf<<<dim3((N_TOT + 63) / 64, SPL_AX), 256, 0, stream>>>(
            Abf, ALDA, xT, KPAD, parts, N_TOT, N_TOT);
        gemm_small2<<<dim3((N_TOT + 15) / 16), 256, 0, stream>>>(
            parts, SPL_AX, XSZ, nullptr,
            Wl + (size_t)l * E_DIM * E_DIM, bl + (size_t)l * E_DIM, x, N_TOT, 1);
    }
    // 4) head: per-row scalar tables, then 3-gather + hardshrink
    head_svec<<<dim3((N_TOT + 63) / 64), 256, 0, stream>>>(x, rsd, wv, svec);
    head_final<<<dim3((M_TPL + 255) / 256), 256, 0, stream>>>(svec, tpl, wv, outp);
}

// Round 7
// 570.756 us; speedup vs baseline: 1.0559x; 1.0559x over previous
//
#include <hip/hip_runtime.h>
#include <hip/hip_bf16.h>

// Problem constants (from reference setup_inputs)
#define F_SIZE 1024
#define E_DIM  128
#define N_D    6000
#define N_SE   1000
#define N_TOT  7000
#define M_TPL  300000
#define LAMB   1e-6f
#define BKT    256    // GEMM k-tile (bf16 elems): 512 B per row per tile
#define KPAD   7168   // 28*256: xT / Abf padded K extent
#define ALDA   7168   // Abf leading dim
#define SPL_AX  10    // split-K for A@x: 110 x-tiles * 10 = 1100 blocks
#define SPL_MLP 4     // split-K for MLP1: 94 * 4 = 376 blocks (KT=4, 1 tile each)
#define SVPAD  7168   // svec row stride

typedef __bf16 bf16x8 __attribute__((ext_vector_type(8)));
typedef float  f32x4  __attribute__((ext_vector_type(4)));
typedef unsigned short u16;

__device__ __forceinline__ float hshrink(float v) {
    return fabsf(v) > LAMB ? v : 0.0f;
}

// RNE float -> bf16 bits (inputs are finite; no NaN handling needed)
__device__ __forceinline__ u16 f2bf(float f) {
    unsigned int u = __builtin_bit_cast(unsigned int, f);
    unsigned int r = u + 0x7fffu + ((u >> 16) & 1u);
    return (u16)(r >> 16);
}

// Async global->LDS DMA, 16B per lane: lane i deposits at ldsbase + i*16.
// Global per-lane address is arbitrary (per-lane scatter allowed on source).
__device__ __forceinline__ void gl_lds16(const void* g, void* l) {
    __builtin_amdgcn_global_load_lds(
        (__attribute__((address_space(1))) void*)(void*)(g),
        (__attribute__((address_space(3))) void*)(l), 16, 0, 0);
}

// ---------------------------------------------------------------------------
// Contiguous streaming fp32 -> bf16 conversion with zero-padded row tail.
// ---------------------------------------------------------------------------
__global__ __launch_bounds__(256) void conv_pad_bf16(const float* __restrict__ src,
                                                     u16* __restrict__ dst,
                                                     int K, int ldp) {
    const int r = blockIdx.x;
    const int chunks = ldp >> 3;
    const float* sp = src + (size_t)r * K;
    u16* dp = dst + (size_t)r * ldp;
    for (int c8 = threadIdx.x; c8 < chunks; c8 += 256) {
        const int c = c8 * 8;
        u16 us[8];
        if (c + 8 <= K) {
            float4 v0 = *(const float4*)(sp + c);
            float4 v1 = *(const float4*)(sp + c + 4);
            us[0] = f2bf(v0.x); us[1] = f2bf(v0.y);
            us[2] = f2bf(v0.z); us[3] = f2bf(v0.w);
            us[4] = f2bf(v1.x); us[5] = f2bf(v1.y);
            us[6] = f2bf(v1.z); us[7] = f2bf(v1.w);
        } else {
#pragma unroll
            for (int i = 0; i < 8; i++)
                us[i] = (c + i < K) ? f2bf(sp[c + i]) : (u16)0;
        }
        *(uint4*)(dp + c) = *(uint4*)us;
    }
}

// ---------------------------------------------------------------------------
// Contiguous-staged MFMA GEMM, split-K (request-granularity fix):
//   Cpart[sp][row][n] = sum_{k tiles} A[row][k] * BT[n][k]
// A bf16 [M][lda], k padded/zeroed to tiles of BKT=256 (512 B per row-chunk).
// Staging: each global_load_lds instruction moves 1 KB = TWO contiguous 512B
// row-chunks (lanes 0-31 row r, lanes 32-63 row r+1) -> 2 segments/instr,
// vs 16x64B scatter of prior versions (the measured ~1.2 TB/s ceiling).
// LDS chunk layout XOR-swizzled via the SOURCE address (linear LDS dest,
// rule-21 pattern): LDS[r][c] = A[r][c ^ (r&31)]; ds_read applies same XOR
// -> 16 fragment lanes spread over 8 bank-groups (2-way, free).
// B (xT, 1.75 MB, L2-resident, reused 110x) is read direct per-fragment.
// 2-barrier m97 loop. LDS 32 KB -> ~5 blocks/CU.
// ---------------------------------------------------------------------------
__global__ __launch_bounds__(256) void gemm_ctg(const u16* __restrict__ A, int lda,
                                                const u16* __restrict__ BT, int ldbt,
                                                float* __restrict__ Cpart,
                                                int M, int KTt) {
    __shared__ u16 As[64 * BKT];    // 32 KB
    const int tid  = threadIdx.x;
    const int lane = tid & 63;
    const int w    = tid >> 6;
    const int fm   = lane & 15;
    const int quad = lane >> 4;
    const int wm   = (w & 1) * 32;
    const int wn   = (w >> 1) * 64;
    const int row0 = blockIdx.x * 64;
    const int sp = blockIdx.y, nsp = gridDim.y;
    const int kt0 = sp * KTt / nsp;
    const int kt1 = (sp + 1) * KTt / nsp;

    // A staging source offsets (u16 units; max 7000*7168 ~ 50.2M fits int).
    // Instruction j stages local rows (w*16+2j, w*16+2j+1); lane supplies
    // chunk (lane&31) of row w*16+2j+(lane>>5), pre-swizzled by ^(rl&31).
    int aOff[8];
#pragma unroll
    for (int j = 0; j < 8; j++) {
        int rl = w * 16 + 2 * j + (lane >> 5);
        int grow = row0 + rl; if (grow > M - 1) grow = M - 1;  // never stored
        int gq = (lane & 31) ^ (rl & 31);
        aOff[j] = grow * lda + gq * 8;
    }
    // B fragment offsets: row (wn+ni*16+fm), k base quad*8.
    int bOff[4];
#pragma unroll
    for (int ni = 0; ni < 4; ni++)
        bOff[ni] = (wn + ni * 16 + fm) * ldbt + quad * 8;

    const f32x4 zero = {0.f, 0.f, 0.f, 0.f};
    f32x4 acc[2][4];
#pragma unroll
    for (int i = 0; i < 2; i++)
#pragma unroll
        for (int j = 0; j < 4; j++) acc[i][j] = zero;

    for (int kt = kt0; kt < kt1; kt++) {
        const int kof = kt * BKT;
        __syncthreads();                 // prior compute done with LDS
#pragma unroll
        for (int j = 0; j < 8; j++)
            gl_lds16(A + aOff[j] + kof, &As[(w * 16 + 2 * j) * BKT]);
        __syncthreads();                 // DMA landed (vmcnt drain)

#pragma unroll
        for (int sub = 0; sub < 8; sub++) {
            bf16x8 af[2], bv[4];
#pragma unroll
            for (int ni = 0; ni < 4; ni++)
                bv[ni] = *(const bf16x8*)(BT + bOff[ni] + kof + sub * 32);
#pragma unroll
            for (int mi = 0; mi < 2; mi++) {
                int r  = wm + mi * 16 + fm;
                int ch = (sub * 4 + quad) ^ (r & 31);
                af[mi] = *(const bf16x8*)&As[r * BKT + ch * 8];
            }
#pragma unroll
            for (int mi = 0; mi < 2; mi++)
#pragma unroll
                for (int ni = 0; ni < 4; ni++)
                    acc[mi][ni] = __builtin_amdgcn_mfma_f32_16x16x32_bf16(
                        af[mi], bv[ni], acc[mi][ni], 0, 0, 0);
        }
    }

    float* op = Cpart + (size_t)sp * M * E_DIM;
#pragma unroll
    for (int mi = 0; mi < 2; mi++) {
#pragma unroll
        for (int rr = 0; rr < 4; rr++) {
            int row = row0 + wm + mi * 16 + quad * 4 + rr;
            if (row < M) {
#pragma unroll
                for (int ni = 0; ni < 4; ni++)
                    op[(size_t)row * E_DIM + wn + ni * 16 + fm] = acc[mi][ni][rr];
            }
        }
    }
}

// ---------------------------------------------------------------------------
// Small GEMM (K=128), BM=16: fuses the split-K reduction of its fp32 A input.
// ---------------------------------------------------------------------------
__global__ __launch_bounds__(256) void gemm_small2(const float* __restrict__ parts,
                                                   int nparts, size_t partStride,
                                                   const float* __restrict__ preBias,
                                                   const float* __restrict__ W,
                                                   const float* __restrict__ bias,
                                                   float* __restrict__ outp,
                                                   int Mrows, int act) {
    __shared__ float Asum[16][132];
    const int tid = threadIdx.x;
    const int row0 = blockIdx.x * 16;
    const int r  = tid >> 4;
    const int kc = (tid & 15) * 8;
    const int grow = row0 + r;

    float4 s0 = make_float4(0.f, 0.f, 0.f, 0.f);
    float4 s1 = make_float4(0.f, 0.f, 0.f, 0.f);
    if (grow < Mrows) {
        for (int s = 0; s < nparts; s++) {
            const float* p = parts + (size_t)s * partStride + (size_t)grow * 128 + kc;
            float4 q0 = *(const float4*)p;
            float4 q1 = *(const float4*)(p + 4);
            s0.x += q0.x; s0.y += q0.y; s0.z += q0.z; s0.w += q0.w;
            s1.x += q1.x; s1.y += q1.y; s1.z += q1.z; s1.w += q1.w;
        }
        if (preBias != nullptr) {
            float4 pb0 = *(const float4*)(preBias + kc);
            float4 pb1 = *(const float4*)(preBias + kc + 4);
            s0.x = fmaxf(s0.x + pb0.x, 0.f); s0.y = fmaxf(s0.y + pb0.y, 0.f);
            s0.z = fmaxf(s0.z + pb0.z, 0.f); s0.w = fmaxf(s0.w + pb0.w, 0.f);
            s1.x = fmaxf(s1.x + pb1.x, 0.f); s1.y = fmaxf(s1.y + pb1.y, 0.f);
            s1.z = fmaxf(s1.z + pb1.z, 0.f); s1.w = fmaxf(s1.w + pb1.w, 0.f);
        }
    }
    *(float4*)&Asum[r][kc]     = s0;
    *(float4*)&Asum[r][kc + 4] = s1;
    __syncthreads();

    float acc[8];
#pragma unroll
    for (int j = 0; j < 8; j++) acc[j] = 0.f;
    const float* wp = W + kc;
#pragma unroll 4
    for (int k = 0; k < 128; k++) {
        float a = Asum[r][k];
        float4 w0 = *(const float4*)(wp + (size_t)k * 128);
        float4 w1 = *(const float4*)(wp + (size_t)k * 128 + 4);
        acc[0] += a * w0.x; acc[1] += a * w0.y;
        acc[2] += a * w0.z; acc[3] += a * w0.w;
        acc[4] += a * w1.x; acc[5] += a * w1.y;
        acc[6] += a * w1.z; acc[7] += a * w1.w;
    }
    if (grow < Mrows) {
        float4 bv0 = *(const float4*)(bias + kc);
        float4 bv1 = *(const float4*)(bias + kc + 4);
        float v[8];
        v[0] = acc[0] + bv0.x; v[1] = acc[1] + bv0.y;
        v[2] = acc[2] + bv0.z; v[3] = acc[3] + bv0.w;
        v[4] = acc[4] + bv1.x; v[5] = acc[5] + bv1.y;
        v[6] = acc[6] + bv1.z; v[7] = acc[7] + bv1.w;
#pragma unroll
        for (int j = 0; j < 8; j++)
            v[j] = (act == 0) ? fmaxf(v[j], 0.f) : hshrink(v[j]);
        float* op = outp + (size_t)grow * 128 + kc;
        *(float4*)op       = make_float4(v[0], v[1], v[2], v[3]);
        *(float4*)(op + 4) = make_float4(v[4], v[5], v[6], v[7]);
    }
}

// ---------------------------------------------------------------------------
__global__ void emb_copy(const float* __restrict__ embSe, float* __restrict__ x) {
    int i = blockIdx.x * blockDim.x + threadIdx.x;
    if (i < N_SE * E_DIM / 4)
        ((float4*)(x + (size_t)N_D * E_DIM))[i] = ((const float4*)embSe)[i];
}

// ---------------------------------------------------------------------------
// src [nrows][128] fp32 -> dst [128][kpad] bf16 (cols >= nrows zero-filled)
// grid: (kpad/64, 2)
// ---------------------------------------------------------------------------
__global__ __launch_bounds__(256) void transpose_bf16(const float* __restrict__ src,
                                                      u16* __restrict__ dst,
                                                      int nrows, int kpad) {
    __shared__ float t[64][65];
    const int r0 = blockIdx.x * 64;
    const int c0 = blockIdx.y * 64;
    const int tid = threadIdx.x;
    {
        const int i  = tid >> 4;          // 0..15
        const int cq = (tid & 15) * 4;
#pragma unroll
        for (int j = 0; j < 4; j++) {
            int r = r0 + i + j * 16;
            float4 v = make_float4(0.f, 0.f, 0.f, 0.f);
            if (r < nrows) v = *(const float4*)(src + (size_t)r * E_DIM + c0 + cq);
            t[i + j * 16][cq + 0] = v.x;
            t[i + j * 16][cq + 1] = v.y;
            t[i + j * 16][cq + 2] = v.z;
            t[i + j * 16][cq + 3] = v.w;
        }
    }
    __syncthreads();
    {
        const int ci = tid >> 2;          // 0..63
        const int rq = (tid & 3) * 16;
        u16 us[16];
#pragma unroll
        for (int j = 0; j < 16; j++) us[j] = f2bf(t[rq + j][ci]);
        u16* dp = dst + (size_t)(c0 + ci) * kpad + r0 + rq;
        *(uint4*)dp       = *(uint4*)&us[0];
        *(uint4*)(dp + 8) = *(uint4*)&us[8];
    }
}

// ---------------------------------------------------------------------------
// Head algebra (inner hardshrink ~= identity at lambda=1e-6):
//   out[m] = HS( s0[d1] + s1[d2] + s2[se] + c0 )
//   s_j[r] = rsd[r] * (x[r] . wv_j),  wv_j = Wp1[j*128:(j+1)*128] @ Wp2
// ---------------------------------------------------------------------------
__global__ __launch_bounds__(256) void head_wvec(const float* __restrict__ Wp1,
                                                 const float* __restrict__ Wp2,
                                                 const float* __restrict__ bp1,
                                                 const float* __restrict__ bp2,
                                                 float* __restrict__ wv) {
    const int tid = threadIdx.x;
#pragma unroll
    for (int rr = 0; rr < 2; rr++) {
        int row = tid + rr * 256;
        if (row < 384) {
            const float* wp = Wp1 + (size_t)row * 128;
            float s = 0.f;
            for (int n = 0; n < 128; n += 4) {
                float4 a = *(const float4*)(wp + n);
                float4 b = *(const float4*)(Wp2 + n);
                s += a.x * b.x + a.y * b.y + a.z * b.z + a.w * b.w;
            }
            wv[row] = s;
        }
    }
    if (tid == 0) {
        float s = 0.f;
        for (int n = 0; n < 128; n++) s += bp1[n] * Wp2[n];
        wv[384] = s + bp2[0];
    }
}

// 64 rows/block, 4 lanes/row (32 cols each). svec[j*SVPAD + r].
__global__ __launch_bounds__(256) void head_svec(const float* __restrict__ x,
                                                 const float* __restrict__ rsd,
                                                 const float* __restrict__ wv,
                                                 float* __restrict__ svec) {
    __shared__ float wvL[384];
    const int tid = threadIdx.x;
    if (tid < 128) {
        wvL[tid]       = wv[tid];
        wvL[tid + 128] = wv[tid + 128];
        wvL[tid + 256] = wv[tid + 256];
    }
    __syncthreads();
    const int sub = tid & 3;
    const int r = blockIdx.x * 64 + (tid >> 2);
    if (r >= N_TOT) return;
    const float* xp = x + (size_t)r * E_DIM + sub * 32;
    float xr[32];
#pragma unroll
    for (int i = 0; i < 8; i++) {
        float4 v = *(const float4*)(xp + i * 4);
        xr[i * 4 + 0] = v.x; xr[i * 4 + 1] = v.y;
        xr[i * 4 + 2] = v.z; xr[i * 4 + 3] = v.w;
    }
    const float sc = rsd[r];
#pragma unroll
    for (int j = 0; j < 3; j++) {
        const float* wp = &wvL[j * 128 + sub * 32];
        float p = 0.f;
#pragma unroll
        for (int i = 0; i < 32; i++) p += xr[i] * wp[i];
        p += __shfl_xor(p, 1, 64);
        p += __shfl_xor(p, 2, 64);
        if (sub == 0) svec[j * SVPAD + r] = sc * p;
    }
}

// One thread per triple: 3 gathers from the 28 KB-per-segment svec tables.
__global__ __launch_bounds__(256) void head_final(const float* __restrict__ svec,
                                                  const int* __restrict__ tpl,
                                                  const float* __restrict__ wv,
                                                  float* __restrict__ outp) {
    int m = blockIdx.x * 256 + threadIdx.x;
    if (m >= M_TPL) return;
    int d1 = tpl[3 * m + 0];
    int d2 = tpl[3 * m + 1];
    int se = tpl[3 * m + 2];
    float c0 = wv[384];
    outp[m] = hshrink(svec[d1] + svec[SVPAD + d2] + svec[2 * SVPAD + se] + c0);
}

// ---------------------------------------------------------------------------
extern "C" void kernel_launch(void* const* d_in, const int* in_sizes, int n_in,
                              void* d_out, int out_size, void* d_ws, size_t ws_size,
                              hipStream_t stream) {
    const float* drugF = (const float*)d_in[0];
    const float* A     = (const float*)d_in[1];
    const int*   tpl   = (const int*)d_in[2];
    const float* rsd   = (const float*)d_in[3];
    const float* W1    = (const float*)d_in[4];
    const float* b1    = (const float*)d_in[5];
    const float* W2    = (const float*)d_in[6];
    const float* b2    = (const float*)d_in[7];
    const float* embSe = (const float*)d_in[8];
    const float* Wl    = (const float*)d_in[9];
    const float* bl    = (const float*)d_in[10];
    const float* Wp1   = (const float*)d_in[11];
    const float* bp1   = (const float*)d_in[12];
    const float* Wp2   = (const float*)d_in[13];
    const float* bp2   = (const float*)d_in[14];
    float* outp = (float*)d_out;

    float* ws = (float*)d_ws;
    const size_t XSZ = (size_t)N_TOT * E_DIM;   // 896000 floats
    const size_t P_AX  = (size_t)SPL_AX * XSZ;
    const size_t P_MLP = (size_t)SPL_MLP * N_D * E_DIM;
    const size_t PARTS = P_AX > P_MLP ? P_AX : P_MLP;
    float* x     = ws;
    float* parts = ws + XSZ;
    u16* xT   = (u16*)(ws + XSZ + PARTS);
    u16* W1T  = xT + (size_t)128 * KPAD;
    float* wv   = (float*)(W1T + (size_t)128 * 1024);   // 385 floats (pad 512)
    float* svec = wv + 512;                              // 3 * SVPAD floats
    u16* Abf  = (u16*)(svec + 3 * SVPAD);                // 7000 x ALDA bf16
    u16* dFbf = Abf + (size_t)N_TOT * ALDA;              // 6000 x 1024 bf16

    // 0) weight conversions + head weight-vector precompute + A/drugF -> bf16
    transpose_bf16<<<dim3(1024 / 64, 2), 256, 0, stream>>>(W1, W1T, F_SIZE, 1024);
    head_wvec<<<dim3(1), 256, 0, stream>>>(Wp1, Wp2, bp1, bp2, wv);
    conv_pad_bf16<<<dim3(N_TOT), 256, 0, stream>>>(A, Abf, N_TOT, ALDA);
    conv_pad_bf16<<<dim3(N_D), 256, 0, stream>>>(drugF, dFbf, F_SIZE, 1024);
    // 1) MLP layer 1 (contiguous-staged split-K; K=1024 -> 4 tiles) + layer 2
    gemm_ctg<<<dim3((N_D + 63) / 64, SPL_MLP), 256, 0, stream>>>(
        dFbf, 1024, W1T, 1024, parts, N_D, F_SIZE / BKT);
    gemm_small2<<<dim3((N_D + 15) / 16), 256, 0, stream>>>(
        parts, SPL_MLP, (size_t)N_D * E_DIM, b1, W2, b2, x, N_D, 0);
    // 2) embSe rows
    emb_copy<<<dim3((N_SE * E_DIM / 4 + 255) / 256), 256, 0, stream>>>(embSe, x);
    // 3) two propagation layers: x = HS( (A@x) @ Wl[i] + bl[i] )
    //    K=7168 padded -> 28 tiles of 256.
    for (int l = 0; l < 2; l++) {
        transpose_bf16<<<dim3(KPAD / 64, 2), 256, 0, stream>>>(x, xT, N_TOT, KPAD);
        gemm_ctg<<<dim3((N_TOT + 63) / 64, SPL_AX), 256, 0, stream>>>(
            Abf, ALDA, xT, KPAD, parts, N_TOT, KPAD / BKT);
        gemm_small2<<<dim3((N_TOT + 15) / 16), 256, 0, stream>>>(
            parts, SPL_AX, XSZ, nullptr,
            Wl + (size_t)l * E_DIM * E_DIM, bl + (size_t)l * E_DIM, x, N_TOT, 1);
    }
    // 4) head: per-row scalar tables, then 3-gather + hardshrink
    head_svec<<<dim3((N_TOT + 63) / 64), 256, 0, stream>>>(x, rsd, wv, svec);
    head_final<<<dim3((M_TPL + 255) / 256), 256, 0, stream>>>(svec, tpl, wv, outp);
}

// Round 8
// 494.034 us; speedup vs baseline: 1.2199x; 1.1553x over previous
//
#include <hip/hip_runtime.h>
#include <hip/hip_bf16.h>

// Problem constants (from reference setup_inputs)
#define F_SIZE 1024
#define E_DIM  128
#define N_D    6000
#define N_SE   1000
#define N_TOT  7000
#define M_TPL  300000
#define LAMB   1e-6f
#define KPAD   7040   // N_TOT rounded up (xT leading dim; 14080 B = 55*256, odd)
#define SPL_AX  7     // split-K for A@x: 110 x-tiles * 7 = 770 blocks (3.0/CU)
#define SPL_MLP 8     // split-K for MLP1: 94 * 8 = 752 blocks
#define SVPAD  7168   // svec row stride

typedef __bf16 bf16x8 __attribute__((ext_vector_type(8)));
typedef float  f32x4  __attribute__((ext_vector_type(4)));
typedef unsigned short u16;

__device__ __forceinline__ float hshrink(float v) {
    return fabsf(v) > LAMB ? v : 0.0f;
}

// RNE float -> bf16 bits (inputs are finite; no NaN handling needed)
__device__ __forceinline__ u16 f2bf(float f) {
    unsigned int u = __builtin_bit_cast(unsigned int, f);
    unsigned int r = u + 0x7fffu + ((u >> 16) & 1u);
    return (u16)(r >> 16);
}

// Async global->LDS DMA, 16B per lane. LDS dest must be wave-uniform;
// each lane deposits at ldsbase + lane*16. Global per-lane address arbitrary.
__device__ __forceinline__ void gl_lds16(const void* g, void* l) {
    __builtin_amdgcn_global_load_lds(
        (__attribute__((address_space(1))) void*)(void*)(g),
        (__attribute__((address_space(3))) void*)(l), 16, 0, 0);
}

// ---------------------------------------------------------------------------
// m97-style MFMA GEMM, split-K (R0-measured 114 us/dispatch on A@x):
//   Cpart[sp][row][n] = sum_{k chunk} A[row][k] * BT[n][k]
// A fp32 [M][lda] staged raw into LDS via global_load_lds (cvt at frag read).
// BT bf16 [128][ldbt] (zero-padded cols). BM=64, BN=128, BK=32.
// 2-barrier K-loop: barrier / DMA-stage / barrier / ds_read+MFMA.
// LDS lane->chunk mapping is XOR-swizzled so frag ds_reads are ~2-way only:
//   As (128B rows, 8 chunks):  LDS(r,j) = global(r, j ^ (r&7))
//   Bs (64B rows, 4 chunks):   LDS(n,j) = global(n, j ^ ((n>>1)&3))
// ---------------------------------------------------------------------------
__global__ __launch_bounds__(256) void gemm_dma(const float* __restrict__ A, int lda,
                                                const u16* __restrict__ BT, int ldbt,
                                                float* __restrict__ Cpart,
                                                int M, int K) {
    __shared__ float As[64 * 32];    // 8 KB
    __shared__ u16   Bs[128 * 32];   // 8 KB
    const int tid  = threadIdx.x;
    const int lane = tid & 63;
    const int w    = tid >> 6;
    const int fm   = lane & 15;
    const int quad = lane >> 4;
    const int wm   = (w & 1) * 32;
    const int wn   = (w >> 1) * 64;
    const int row0 = blockIdx.x * 64;
    const int sp = blockIdx.y, nsp = gridDim.y;
    const int KT  = (K + 31) / 32;
    const int kt0 = sp * KT / nsp;
    const int kt1 = (sp + 1) * KT / nsp;

    // A staging: wave w stages local rows [w*16, w*16+16), 2 instr x 8 rows.
    int aLoc[2], aQ[2];
    const float* aG[2];
#pragma unroll
    for (int j = 0; j < 2; j++) {
        int r = w * 16 + j * 8 + (lane >> 3);   // local row 0..63
        aLoc[j] = r;
        int grow = row0 + r; if (grow > M - 1) grow = M - 1;
        aQ[j] = (lane & 7) ^ (r & 7);
        aG[j] = A + (size_t)grow * lda + aQ[j] * 4;
    }
    // B staging: wave w stages rows [w*32, w*32+32), 2 instr x 16 rows.
    const u16* bG[2];
#pragma unroll
    for (int j = 0; j < 2; j++) {
        int n = w * 32 + j * 16 + (lane >> 2);
        int q = (lane & 3) ^ ((n >> 1) & 3);
        bG[j] = BT + (size_t)n * ldbt + q * 8;
    }

    const f32x4 zero = {0.f, 0.f, 0.f, 0.f};
    f32x4 acc[2][4];
#pragma unroll
    for (int i = 0; i < 2; i++)
#pragma unroll
        for (int j = 0; j < 4; j++) acc[i][j] = zero;

    for (int kt = kt0; kt < kt1; kt++) {
        const int k0 = kt * 32;
        __syncthreads();                    // previous compute done with LDS
        if (k0 + 32 <= K) {
#pragma unroll
            for (int j = 0; j < 2; j++)
                gl_lds16(aG[j] + k0, &As[(w * 16 + j * 8) * 32]);
        } else {
            // masked tail tile (K not multiple of 32; chunks are 4-aligned)
#pragma unroll
            for (int j = 0; j < 2; j++) {
                float4 v = make_float4(0.f, 0.f, 0.f, 0.f);
                if (k0 + aQ[j] * 4 + 4 <= K) v = *(const float4*)(aG[j] + k0);
                *(float4*)&As[aLoc[j] * 32 + (lane & 7) * 4] = v;
            }
        }
#pragma unroll
        for (int j = 0; j < 2; j++)
            gl_lds16(bG[j] + k0, &Bs[(w * 32 + j * 16) * 32]);
        __syncthreads();                    // DMA landed (vmcnt drain)

        bf16x8 bfr[4];
#pragma unroll
        for (int ni = 0; ni < 4; ni++) {
            int n = wn + ni * 16 + fm;
            bfr[ni] = *(const bf16x8*)&Bs[n * 32 + (quad ^ ((n >> 1) & 3)) * 8];
        }
#pragma unroll
        for (int mi = 0; mi < 2; mi++) {
            int r = wm + mi * 16 + fm;
            int s = r & 7;
            f32x4 f0 = *(const f32x4*)&As[r * 32 + ((quad * 2) ^ s) * 4];
            f32x4 f1 = *(const f32x4*)&As[r * 32 + ((quad * 2 + 1) ^ s) * 4];
            u16 us[8];
            us[0] = f2bf(f0[0]); us[1] = f2bf(f0[1]);
            us[2] = f2bf(f0[2]); us[3] = f2bf(f0[3]);
            us[4] = f2bf(f1[0]); us[5] = f2bf(f1[1]);
            us[6] = f2bf(f1[2]); us[7] = f2bf(f1[3]);
            bf16x8 af = *(bf16x8*)us;
#pragma unroll
            for (int ni = 0; ni < 4; ni++)
                acc[mi][ni] = __builtin_amdgcn_mfma_f32_16x16x32_bf16(
                    af, bfr[ni], acc[mi][ni], 0, 0, 0);
        }
    }

    float* op = Cpart + (size_t)sp * M * E_DIM;
#pragma unroll
    for (int mi = 0; mi < 2; mi++) {
#pragma unroll
        for (int rr = 0; rr < 4; rr++) {
            int row = row0 + wm + mi * 16 + quad * 4 + rr;
            if (row < M) {
#pragma unroll
                for (int ni = 0; ni < 4; ni++)
                    op[(size_t)row * E_DIM + wn + ni * 16 + fm] = acc[mi][ni][rr];
            }
        }
    }
}

// ---------------------------------------------------------------------------
// Small GEMM (K=128), BM=16: fuses the split-K reduction of its fp32 A input.
// ---------------------------------------------------------------------------
__global__ __launch_bounds__(256) void gemm_small2(const float* __restrict__ parts,
                                                   int nparts, size_t partStride,
                                                   const float* __restrict__ preBias,
                                                   const float* __restrict__ W,
                                                   const float* __restrict__ bias,
                                                   float* __restrict__ outp,
                                                   int Mrows, int act) {
    __shared__ float Asum[16][132];
    const int tid = threadIdx.x;
    const int row0 = blockIdx.x * 16;
    const int r  = tid >> 4;
    const int kc = (tid & 15) * 8;
    const int grow = row0 + r;

    float4 s0 = make_float4(0.f, 0.f, 0.f, 0.f);
    float4 s1 = make_float4(0.f, 0.f, 0.f, 0.f);
    if (grow < Mrows) {
        for (int s = 0; s < nparts; s++) {
            const float* p = parts + (size_t)s * partStride + (size_t)grow * 128 + kc;
            float4 q0 = *(const float4*)p;
            float4 q1 = *(const float4*)(p + 4);
            s0.x += q0.x; s0.y += q0.y; s0.z += q0.z; s0.w += q0.w;
            s1.x += q1.x; s1.y += q1.y; s1.z += q1.z; s1.w += q1.w;
        }
        if (preBias != nullptr) {
            float4 pb0 = *(const float4*)(preBias + kc);
            float4 pb1 = *(const float4*)(preBias + kc + 4);
            s0.x = fmaxf(s0.x + pb0.x, 0.f); s0.y = fmaxf(s0.y + pb0.y, 0.f);
            s0.z = fmaxf(s0.z + pb0.z, 0.f); s0.w = fmaxf(s0.w + pb0.w, 0.f);
            s1.x = fmaxf(s1.x + pb1.x, 0.f); s1.y = fmaxf(s1.y + pb1.y, 0.f);
            s1.z = fmaxf(s1.z + pb1.z, 0.f); s1.w = fmaxf(s1.w + pb1.w, 0.f);
        }
    }
    *(float4*)&Asum[r][kc]     = s0;
    *(float4*)&Asum[r][kc + 4] = s1;
    __syncthreads();

    float acc[8];
#pragma unroll
    for (int j = 0; j < 8; j++) acc[j] = 0.f;
    const float* wp = W + kc;
#pragma unroll 4
    for (int k = 0; k < 128; k++) {
        float a = Asum[r][k];
        float4 w0 = *(const float4*)(wp + (size_t)k * 128);
        float4 w1 = *(const float4*)(wp + (size_t)k * 128 + 4);
        acc[0] += a * w0.x; acc[1] += a * w0.y;
        acc[2] += a * w0.z; acc[3] += a * w0.w;
        acc[4] += a * w1.x; acc[5] += a * w1.y;
        acc[6] += a * w1.z; acc[7] += a * w1.w;
    }
    if (grow < Mrows) {
        float4 bv0 = *(const float4*)(bias + kc);
        float4 bv1 = *(const float4*)(bias + kc + 4);
        float v[8];
        v[0] = acc[0] + bv0.x; v[1] = acc[1] + bv0.y;
        v[2] = acc[2] + bv0.z; v[3] = acc[3] + bv0.w;
        v[4] = acc[4] + bv1.x; v[5] = acc[5] + bv1.y;
        v[6] = acc[6] + bv1.z; v[7] = acc[7] + bv1.w;
#pragma unroll
        for (int j = 0; j < 8; j++)
            v[j] = (act == 0) ? fmaxf(v[j], 0.f) : hshrink(v[j]);
        float* op = outp + (size_t)grow * 128 + kc;
        *(float4*)op       = make_float4(v[0], v[1], v[2], v[3]);
        *(float4*)(op + 4) = make_float4(v[4], v[5], v[6], v[7]);
    }
}

// ---------------------------------------------------------------------------
__global__ void emb_copy(const float* __restrict__ embSe, float* __restrict__ x) {
    int i = blockIdx.x * blockDim.x + threadIdx.x;
    if (i < N_SE * E_DIM / 4)
        ((float4*)(x + (size_t)N_D * E_DIM))[i] = ((const float4*)embSe)[i];
}

// ---------------------------------------------------------------------------
// src [nrows][128] fp32 -> dst [128][kpad] bf16 (cols >= nrows zero-filled)
// grid: (kpad/64, 2)
// ---------------------------------------------------------------------------
__global__ __launch_bounds__(256) void transpose_bf16(const float* __restrict__ src,
                                                      u16* __restrict__ dst,
                                                      int nrows, int kpad) {
    __shared__ float t[64][65];
    const int r0 = blockIdx.x * 64;
    const int c0 = blockIdx.y * 64;
    const int tid = threadIdx.x;
    {
        const int i  = tid >> 4;          // 0..15
        const int cq = (tid & 15) * 4;
#pragma unroll
        for (int j = 0; j < 4; j++) {
            int r = r0 + i + j * 16;
            float4 v = make_float4(0.f, 0.f, 0.f, 0.f);
            if (r < nrows) v = *(const float4*)(src + (size_t)r * E_DIM + c0 + cq);
            t[i + j * 16][cq + 0] = v.x;
            t[i + j * 16][cq + 1] = v.y;
            t[i + j * 16][cq + 2] = v.z;
            t[i + j * 16][cq + 3] = v.w;
        }
    }
    __syncthreads();
    {
        const int ci = tid >> 2;          // 0..63
        const int rq = (tid & 3) * 16;
        u16 us[16];
#pragma unroll
        for (int j = 0; j < 16; j++) us[j] = f2bf(t[rq + j][ci]);
        u16* dp = dst + (size_t)(c0 + ci) * kpad + r0 + rq;
        *(uint4*)dp       = *(uint4*)&us[0];
        *(uint4*)(dp + 8) = *(uint4*)&us[8];
    }
}

// ---------------------------------------------------------------------------
// Head algebra (inner hardshrink ~= identity at lambda=1e-6; induced error
// ~1e-8 << bf16 path error already accepted):
//   out[m] = HS( s0[d1] + s1[d2] + s2[se] + c0 )
//   s_j[r] = rsd[r] * (x[r] . wv_j),  wv_j = Wp1[j*128:(j+1)*128] @ Wp2
//   c0 = bp1.Wp2 + bp2
// ---------------------------------------------------------------------------
__global__ __launch_bounds__(256) void head_wvec(const float* __restrict__ Wp1,
                                                 const float* __restrict__ Wp2,
                                                 const float* __restrict__ bp1,
                                                 const float* __restrict__ bp2,
                                                 float* __restrict__ wv) {
    const int tid = threadIdx.x;
#pragma unroll
    for (int rr = 0; rr < 2; rr++) {
        int row = tid + rr * 256;
        if (row < 384) {
            const float* wp = Wp1 + (size_t)row * 128;
            float s = 0.f;
            for (int n = 0; n < 128; n += 4) {
                float4 a = *(const float4*)(wp + n);
                float4 b = *(const float4*)(Wp2 + n);
                s += a.x * b.x + a.y * b.y + a.z * b.z + a.w * b.w;
            }
            wv[row] = s;
        }
    }
    if (tid == 0) {
        float s = 0.f;
        for (int n = 0; n < 128; n++) s += bp1[n] * Wp2[n];
        wv[384] = s + bp2[0];
    }
}

// 64 rows/block, 4 lanes/row (32 cols each). svec[j*SVPAD + r].
__global__ __launch_bounds__(256) void head_svec(const float* __restrict__ x,
                                                 const float* __restrict__ rsd,
                                                 const float* __restrict__ wv,
                                                 float* __restrict__ svec) {
    __shared__ float wvL[384];
    const int tid = threadIdx.x;
    if (tid < 128) {
        wvL[tid]       = wv[tid];
        wvL[tid + 128] = wv[tid + 128];
        wvL[tid + 256] = wv[tid + 256];
    }
    __syncthreads();
    const int sub = tid & 3;
    const int r = blockIdx.x * 64 + (tid >> 2);
    if (r >= N_TOT) return;
    const float* xp = x + (size_t)r * E_DIM + sub * 32;
    float xr[32];
#pragma unroll
    for (int i = 0; i < 8; i++) {
        float4 v = *(const float4*)(xp + i * 4);
        xr[i * 4 + 0] = v.x; xr[i * 4 + 1] = v.y;
        xr[i * 4 + 2] = v.z; xr[i * 4 + 3] = v.w;
    }
    const float sc = rsd[r];
#pragma unroll
    for (int j = 0; j < 3; j++) {
        const float* wp = &wvL[j * 128 + sub * 32];
        float p = 0.f;
#pragma unroll
        for (int i = 0; i < 32; i++) p += xr[i] * wp[i];
        p += __shfl_xor(p, 1, 64);
        p += __shfl_xor(p, 2, 64);
        if (sub == 0) svec[j * SVPAD + r] = sc * p;
    }
}

// One thread per triple: 3 gathers from the 28 KB-per-segment svec tables.
__global__ __launch_bounds__(256) void head_final(const float* __restrict__ svec,
                                                  const int* __restrict__ tpl,
                                                  const float* __restrict__ wv,
                                                  float* __restrict__ outp) {
    int m = blockIdx.x * 256 + threadIdx.x;
    if (m >= M_TPL) return;
    int d1 = tpl[3 * m + 0];
    int d2 = tpl[3 * m + 1];
    int se = tpl[3 * m + 2];
    float c0 = wv[384];
    outp[m] = hshrink(svec[d1] + svec[SVPAD + d2] + svec[2 * SVPAD + se] + c0);
}

// ---------------------------------------------------------------------------
extern "C" void kernel_launch(void* const* d_in, const int* in_sizes, int n_in,
                              void* d_out, int out_size, void* d_ws, size_t ws_size,
                              hipStream_t stream) {
    const float* drugF = (const float*)d_in[0];
    const float* A     = (const float*)d_in[1];
    const int*   tpl   = (const int*)d_in[2];
    const float* rsd   = (const float*)d_in[3];
    const float* W1    = (const float*)d_in[4];
    const float* b1    = (const float*)d_in[5];
    const float* W2    = (const float*)d_in[6];
    const float* b2    = (const float*)d_in[7];
    const float* embSe = (const float*)d_in[8];
    const float* Wl    = (const float*)d_in[9];
    const float* bl    = (const float*)d_in[10];
    const float* Wp1   = (const float*)d_in[11];
    const float* bp1   = (const float*)d_in[12];
    const float* Wp2   = (const float*)d_in[13];
    const float* bp2   = (const float*)d_in[14];
    float* outp = (float*)d_out;

    float* ws = (float*)d_ws;
    const size_t XSZ = (size_t)N_TOT * E_DIM;   // 896000 floats
    const size_t P_AX  = (size_t)SPL_AX * XSZ;               // 6.272M floats
    const size_t P_MLP = (size_t)SPL_MLP * N_D * E_DIM;      // 6.144M floats
    const size_t PARTS = P_AX > P_MLP ? P_AX : P_MLP;
    float* x     = ws;
    float* parts = ws + XSZ;
    u16* xT   = (u16*)(ws + XSZ + PARTS);
    u16* W1T  = xT + (size_t)128 * KPAD;
    float* wv   = (float*)(W1T + (size_t)128 * 1024);   // 385 floats (pad 512)
    float* svec = wv + 512;                              // 3 * SVPAD floats

    // 0) W1 -> bf16 transpose + head weight-vector precompute
    transpose_bf16<<<dim3(1024 / 64, 2), 256, 0, stream>>>(W1, W1T, F_SIZE, 1024);
    head_wvec<<<dim3(1), 256, 0, stream>>>(Wp1, Wp2, bp1, bp2, wv);
    // 1) MLP layer 1 (DMA-staged bf16 MFMA split-K) + fused-reduce MLP layer 2
    gemm_dma<<<dim3((N_D + 63) / 64, SPL_MLP), 256, 0, stream>>>(
        drugF, F_SIZE, W1T, 1024, parts, N_D, F_SIZE);
    gemm_small2<<<dim3((N_D + 15) / 16), 256, 0, stream>>>(
        parts, SPL_MLP, (size_t)N_D * E_DIM, b1, W2, b2, x, N_D, 0);
    // 2) embSe rows
    emb_copy<<<dim3((N_SE * E_DIM / 4 + 255) / 256), 256, 0, stream>>>(embSe, x);
    // 3) two propagation layers: x = HS( (A@x) @ Wl[i] + bl[i] )
    for (int l = 0; l < 2; l++) {
        transpose_bf16<<<dim3(KPAD / 64, 2), 256, 0, stream>>>(x, xT, N_TOT, KPAD);
        gemm_dma<<<dim3((N_TOT + 63) / 64, SPL_AX), 256, 0, stream>>>(
            A, N_TOT, xT, KPAD, parts, N_TOT, N_TOT);
        gemm_small2<<<dim3((N_TOT + 15) / 16), 256, 0, stream>>>(
            parts, SPL_AX, XSZ, nullptr,
            Wl + (size_t)l * E_DIM * E_DIM, bl + (size_t)l * E_DIM, x, N_TOT, 1);
    }
    // 4) head: per-row scalar tables, then 3-gather + hardshrink
    head_svec<<<dim3((N_TOT + 63) / 64), 256, 0, stream>>>(x, rsd, wv, svec);
    head_final<<<dim3((M_TPL + 255) / 256), 256, 0, stream>>>(svec, tpl, wv, outp);
}

// Round 9
// 484.762 us; speedup vs baseline: 1.2432x; 1.0191x over previous
//
#include <hip/hip_runtime.h>
#include <hip/hip_bf16.h>

// Problem constants (from reference setup_inputs)
#define F_SIZE 1024
#define E_DIM  128
#define N_D    6000
#define N_SE   1000
#define N_TOT  7000
#define M_TPL  300000
#define LAMB   1e-6f
#define KPAD   7040   // N_TOT rounded up (xT leading dim)
#define SPL_AX  9     // split-K for A@x: 110 x-tiles * 9 = 990 blocks (~3.9/CU)
#define SPL_MLP 8     // split-K for MLP1: 94 * 8 = 752 blocks
#define SVPAD  7168   // svec row stride

typedef __bf16 bf16x8 __attribute__((ext_vector_type(8)));
typedef float  f32x4  __attribute__((ext_vector_type(4)));
typedef unsigned short u16;

__device__ __forceinline__ float hshrink(float v) {
    return fabsf(v) > LAMB ? v : 0.0f;
}

// RNE float -> bf16 bits (inputs are finite; no NaN handling needed)
__device__ __forceinline__ u16 f2bf(float f) {
    unsigned int u = __builtin_bit_cast(unsigned int, f);
    unsigned int r = u + 0x7fffu + ((u >> 16) & 1u);
    return (u16)(r >> 16);
}

// Async global->LDS DMA, 16B per lane. LDS dest must be wave-uniform;
// each lane deposits at ldsbase + lane*16. Global per-lane address arbitrary.
__device__ __forceinline__ void gl_lds16(const void* g, void* l) {
    __builtin_amdgcn_global_load_lds(
        (__attribute__((address_space(1))) void*)(void*)(g),
        (__attribute__((address_space(3))) void*)(l), 16, 0, 0);
}

// ---------------------------------------------------------------------------
// m97-style MFMA GEMM, split-K, NOW with 2-deep LDS double-buffer and
// counted vmcnt (never 0 in the pipelined loop):
//   per iter: STAGE(t+1 -> buf^1) | vmcnt(4) [tile t landed, t+1 in flight]
//             | s_barrier | COMPUTE(buf) | s_barrier
// Loads for t+1 stay in flight across compute+barriers -> memory duty cycle
// goes from bursty (full vmcnt(0) drain each iter, r8: 1.16 TB/s) to
// sustained. Each wave issues exactly 4 gl_lds16 per stage (2 A + 2 B), so
// vmcnt(4) == "my previous stage has landed".
// Masked tail tile (K % 32 != 0, last split only) runs un-pipelined after.
// ---------------------------------------------------------------------------
__global__ __launch_bounds__(256) void gemm_dma(const float* __restrict__ A, int lda,
                                                const u16* __restrict__ BT, int ldbt,
                                                float* __restrict__ Cpart,
                                                int M, int K) {
    __shared__ float As[2][64 * 32];    // 2 x 8 KB
    __shared__ u16   Bs[2][128 * 32];   // 2 x 8 KB
    const int tid  = threadIdx.x;
    const int lane = tid & 63;
    const int w    = tid >> 6;
    const int fm   = lane & 15;
    const int quad = lane >> 4;
    const int wm   = (w & 1) * 32;
    const int wn   = (w >> 1) * 64;
    const int row0 = blockIdx.x * 64;
    const int sp = blockIdx.y, nsp = gridDim.y;
    const int KT  = (K + 31) / 32;
    const int kt0 = sp * KT / nsp;
    const int kt1 = (sp + 1) * KT / nsp;
    const int ktFall = K >> 5;                       // global # full tiles
    const int ktF = kt1 < ktFall ? kt1 : ktFall;     // full tiles in my range

    // A staging: wave w stages local rows [w*16, w*16+16), 2 instr x 8 rows.
    int aLoc[2], aQ[2];
    const float* aG[2];
#pragma unroll
    for (int j = 0; j < 2; j++) {
        int r = w * 16 + j * 8 + (lane >> 3);   // local row 0..63
        aLoc[j] = r;
        int grow = row0 + r; if (grow > M - 1) grow = M - 1;
        aQ[j] = (lane & 7) ^ (r & 7);
        aG[j] = A + (size_t)grow * lda + aQ[j] * 4;
    }
    // B staging: wave w stages rows [w*32, w*32+32), 2 instr x 16 rows.
    const u16* bG[2];
#pragma unroll
    for (int j = 0; j < 2; j++) {
        int n = w * 32 + j * 16 + (lane >> 2);
        int q = (lane & 3) ^ ((n >> 1) & 3);
        bG[j] = BT + (size_t)n * ldbt + q * 8;
    }

    const f32x4 zero = {0.f, 0.f, 0.f, 0.f};
    f32x4 acc[2][4];
#pragma unroll
    for (int i = 0; i < 2; i++)
#pragma unroll
        for (int j = 0; j < 4; j++) acc[i][j] = zero;

#define STAGE_T(buf, kt)                                                      \
    {                                                                         \
        const int k0s = (kt) * 32;                                            \
        _Pragma("unroll") for (int j = 0; j < 2; j++)                         \
            gl_lds16(aG[j] + k0s, &As[buf][(w * 16 + j * 8) * 32]);           \
        _Pragma("unroll") for (int j = 0; j < 2; j++)                         \
            gl_lds16(bG[j] + k0s, &Bs[buf][(w * 32 + j * 16) * 32]);          \
    }

#define COMPUTE_T(buf)                                                        \
    {                                                                         \
        bf16x8 bfr[4];                                                        \
        _Pragma("unroll") for (int ni = 0; ni < 4; ni++) {                    \
            int n = wn + ni * 16 + fm;                                        \
            bfr[ni] = *(const bf16x8*)&Bs[buf][n * 32 +                       \
                                              (quad ^ ((n >> 1) & 3)) * 8];   \
        }                                                                     \
        _Pragma("unroll") for (int mi = 0; mi < 2; mi++) {                    \
            int r = wm + mi * 16 + fm;                                        \
            int s = r & 7;                                                    \
            f32x4 f0 = *(const f32x4*)&As[buf][r * 32 + ((quad * 2) ^ s) * 4];\
            f32x4 f1 = *(const f32x4*)&As[buf][r * 32 +                       \
                                              ((quad * 2 + 1) ^ s) * 4];      \
            u16 us[8];                                                        \
            us[0] = f2bf(f0[0]); us[1] = f2bf(f0[1]);                         \
            us[2] = f2bf(f0[2]); us[3] = f2bf(f0[3]);                         \
            us[4] = f2bf(f1[0]); us[5] = f2bf(f1[1]);                         \
            us[6] = f2bf(f1[2]); us[7] = f2bf(f1[3]);                         \
            bf16x8 af = *(bf16x8*)us;                                         \
            _Pragma("unroll") for (int ni = 0; ni < 4; ni++)                  \
                acc[mi][ni] = __builtin_amdgcn_mfma_f32_16x16x32_bf16(        \
                    af, bfr[ni], acc[mi][ni], 0, 0, 0);                       \
        }                                                                     \
    }

    if (ktF > kt0) {
        STAGE_T(0, kt0);
        for (int t = kt0; t < ktF; t++) {
            const int cur = (t - kt0) & 1;
            if (t + 1 < ktF) {
                STAGE_T(cur ^ 1, t + 1);        // issue next tile's 4 loads
                // wait for tile t's 4 loads only; t+1's stay in flight
                asm volatile("s_waitcnt vmcnt(4)" ::: "memory");
            } else {
                asm volatile("s_waitcnt vmcnt(0)" ::: "memory");
            }
            __builtin_amdgcn_s_barrier();       // all waves: tile t landed
            COMPUTE_T(cur);
            __builtin_amdgcn_s_barrier();       // all waves done reading buf
        }
    }
    // Masked tail tile (only the last split, K%32 != 0) — un-pipelined.
    for (int kt = ktF; kt < kt1; kt++) {
        const int k0 = kt * 32;
        __syncthreads();
#pragma unroll
        for (int j = 0; j < 2; j++) {
            float4 v = make_float4(0.f, 0.f, 0.f, 0.f);
            if (k0 + aQ[j] * 4 + 4 <= K) v = *(const float4*)(aG[j] + k0);
            *(float4*)&As[0][aLoc[j] * 32 + (lane & 7) * 4] = v;
        }
#pragma unroll
        for (int j = 0; j < 2; j++)
            gl_lds16(bG[j] + k0, &Bs[0][(w * 32 + j * 16) * 32]);
        __syncthreads();
        COMPUTE_T(0);
    }
#undef STAGE_T
#undef COMPUTE_T

    float* op = Cpart + (size_t)sp * M * E_DIM;
#pragma unroll
    for (int mi = 0; mi < 2; mi++) {
#pragma unroll
        for (int rr = 0; rr < 4; rr++) {
            int row = row0 + wm + mi * 16 + quad * 4 + rr;
            if (row < M) {
#pragma unroll
                for (int ni = 0; ni < 4; ni++)
                    op[(size_t)row * E_DIM + wn + ni * 16 + fm] = acc[mi][ni][rr];
            }
        }
    }
}

// ---------------------------------------------------------------------------
// Small GEMM (K=128), BM=16: fuses the split-K reduction of its fp32 A input.
// ---------------------------------------------------------------------------
__global__ __launch_bounds__(256) void gemm_small2(const float* __restrict__ parts,
                                                   int nparts, size_t partStride,
                                                   const float* __restrict__ preBias,
                                                   const float* __restrict__ W,
                                                   const float* __restrict__ bias,
                                                   float* __restrict__ outp,
                                                   int Mrows, int act) {
    __shared__ float Asum[16][132];
    const int tid = threadIdx.x;
    const int row0 = blockIdx.x * 16;
    const int r  = tid >> 4;
    const int kc = (tid & 15) * 8;
    const int grow = row0 + r;

    float4 s0 = make_float4(0.f, 0.f, 0.f, 0.f);
    float4 s1 = make_float4(0.f, 0.f, 0.f, 0.f);
    if (grow < Mrows) {
        for (int s = 0; s < nparts; s++) {
            const float* p = parts + (size_t)s * partStride + (size_t)grow * 128 + kc;
            float4 q0 = *(const float4*)p;
            float4 q1 = *(const float4*)(p + 4);
            s0.x += q0.x; s0.y += q0.y; s0.z += q0.z; s0.w += q0.w;
            s1.x += q1.x; s1.y += q1.y; s1.z += q1.z; s1.w += q1.w;
        }
        if (preBias != nullptr) {
            float4 pb0 = *(const float4*)(preBias + kc);
            float4 pb1 = *(const float4*)(preBias + kc + 4);
            s0.x = fmaxf(s0.x + pb0.x, 0.f); s0.y = fmaxf(s0.y + pb0.y, 0.f);
            s0.z = fmaxf(s0.z + pb0.z, 0.f); s0.w = fmaxf(s0.w + pb0.w, 0.f);
            s1.x = fmaxf(s1.x + pb1.x, 0.f); s1.y = fmaxf(s1.y + pb1.y, 0.f);
            s1.z = fmaxf(s1.z + pb1.z, 0.f); s1.w = fmaxf(s1.w + pb1.w, 0.f);
        }
    }
    *(float4*)&Asum[r][kc]     = s0;
    *(float4*)&Asum[r][kc + 4] = s1;
    __syncthreads();

    float acc[8];
#pragma unroll
    for (int j = 0; j < 8; j++) acc[j] = 0.f;
    const float* wp = W + kc;
#pragma unroll 4
    for (int k = 0; k < 128; k++) {
        float a = Asum[r][k];
        float4 w0 = *(const float4*)(wp + (size_t)k * 128);
        float4 w1 = *(const float4*)(wp + (size_t)k * 128 + 4);
        acc[0] += a * w0.x; acc[1] += a * w0.y;
        acc[2] += a * w0.z; acc[3] += a * w0.w;
        acc[4] += a * w1.x; acc[5] += a * w1.y;
        acc[6] += a * w1.z; acc[7] += a * w1.w;
    }
    if (grow < Mrows) {
        float4 bv0 = *(const float4*)(bias + kc);
        float4 bv1 = *(const float4*)(bias + kc + 4);
        float v[8];
        v[0] = acc[0] + bv0.x; v[1] = acc[1] + bv0.y;
        v[2] = acc[2] + bv0.z; v[3] = acc[3] + bv0.w;
        v[4] = acc[4] + bv1.x; v[5] = acc[5] + bv1.y;
        v[6] = acc[6] + bv1.z; v[7] = acc[7] + bv1.w;
#pragma unroll
        for (int j = 0; j < 8; j++)
            v[j] = (act == 0) ? fmaxf(v[j], 0.f) : hshrink(v[j]);
        float* op = outp + (size_t)grow * 128 + kc;
        *(float4*)op       = make_float4(v[0], v[1], v[2], v[3]);
        *(float4*)(op + 4) = make_float4(v[4], v[5], v[6], v[7]);
    }
}

// ---------------------------------------------------------------------------
__global__ void emb_copy(const float* __restrict__ embSe, float* __restrict__ x) {
    int i = blockIdx.x * blockDim.x + threadIdx.x;
    if (i < N_SE * E_DIM / 4)
        ((float4*)(x + (size_t)N_D * E_DIM))[i] = ((const float4*)embSe)[i];
}

// ---------------------------------------------------------------------------
// src [nrows][128] fp32 -> dst [128][kpad] bf16 (cols >= nrows zero-filled)
// grid: (kpad/64, 2)
// ---------------------------------------------------------------------------
__global__ __launch_bounds__(256) void transpose_bf16(const float* __restrict__ src,
                                                      u16* __restrict__ dst,
                                                      int nrows, int kpad) {
    __shared__ float t[64][65];
    const int r0 = blockIdx.x * 64;
    const int c0 = blockIdx.y * 64;
    const int tid = threadIdx.x;
    {
        const int i  = tid >> 4;          // 0..15
        const int cq = (tid & 15) * 4;
#pragma unroll
        for (int j = 0; j < 4; j++) {
            int r = r0 + i + j * 16;
            float4 v = make_float4(0.f, 0.f, 0.f, 0.f);
            if (r < nrows) v = *(const float4*)(src + (size_t)r * E_DIM + c0 + cq);
            t[i + j * 16][cq + 0] = v.x;
            t[i + j * 16][cq + 1] = v.y;
            t[i + j * 16][cq + 2] = v.z;
            t[i + j * 16][cq + 3] = v.w;
        }
    }
    __syncthreads();
    {
        const int ci = tid >> 2;          // 0..63
        const int rq = (tid & 3) * 16;
        u16 us[16];
#pragma unroll
        for (int j = 0; j < 16; j++) us[j] = f2bf(t[rq + j][ci]);
        u16* dp = dst + (size_t)(c0 + ci) * kpad + r0 + rq;
        *(uint4*)dp       = *(uint4*)&us[0];
        *(uint4*)(dp + 8) = *(uint4*)&us[8];
    }
}

// ---------------------------------------------------------------------------
// Head algebra (inner hardshrink ~= identity at lambda=1e-6; induced error
// ~1e-8 << bf16 path error already accepted):
//   out[m] = HS( s0[d1] + s1[d2] + s2[se] + c0 )
//   s_j[r] = rsd[r] * (x[r] . wv_j),  wv_j = Wp1[j*128:(j+1)*128] @ Wp2
//   c0 = bp1.Wp2 + bp2
// ---------------------------------------------------------------------------
__global__ __launch_bounds__(256) void head_wvec(const float* __restrict__ Wp1,
                                                 const float* __restrict__ Wp2,
                                                 const float* __restrict__ bp1,
                                                 const float* __restrict__ bp2,
                                                 float* __restrict__ wv) {
    const int tid = threadIdx.x;
#pragma unroll
    for (int rr = 0; rr < 2; rr++) {
        int row = tid + rr * 256;
        if (row < 384) {
            const float* wp = Wp1 + (size_t)row * 128;
            float s = 0.f;
            for (int n = 0; n < 128; n += 4) {
                float4 a = *(const float4*)(wp + n);
                float4 b = *(const float4*)(Wp2 + n);
                s += a.x * b.x + a.y * b.y + a.z * b.z + a.w * b.w;
            }
            wv[row] = s;
        }
    }
    if (tid == 0) {
        float s = 0.f;
        for (int n = 0; n < 128; n++) s += bp1[n] * Wp2[n];
        wv[384] = s + bp2[0];
    }
}

// 64 rows/block, 4 lanes/row (32 cols each). svec[j*SVPAD + r].
__global__ __launch_bounds__(256) void head_svec(const float* __restrict__ x,
                                                 const float* __restrict__ rsd,
                                                 const float* __restrict__ wv,
                                                 float* __restrict__ svec) {
    __shared__ float wvL[384];
    const int tid = threadIdx.x;
    if (tid < 128) {
        wvL[tid]       = wv[tid];
        wvL[tid + 128] = wv[tid + 128];
        wvL[tid + 256] = wv[tid + 256];
    }
    __syncthreads();
    const int sub = tid & 3;
    const int r = blockIdx.x * 64 + (tid >> 2);
    if (r >= N_TOT) return;
    const float* xp = x + (size_t)r * E_DIM + sub * 32;
    float xr[32];
#pragma unroll
    for (int i = 0; i < 8; i++) {
        float4 v = *(const float4*)(xp + i * 4);
        xr[i * 4 + 0] = v.x; xr[i * 4 + 1] = v.y;
        xr[i * 4 + 2] = v.z; xr[i * 4 + 3] = v.w;
    }
    const float sc = rsd[r];
#pragma unroll
    for (int j = 0; j < 3; j++) {
        const float* wp = &wvL[j * 128 + sub * 32];
        float p = 0.f;
#pragma unroll
        for (int i = 0; i < 32; i++) p += xr[i] * wp[i];
        p += __shfl_xor(p, 1, 64);
        p += __shfl_xor(p, 2, 64);
        if (sub == 0) svec[j * SVPAD + r] = sc * p;
    }
}

// One thread per triple: 3 gathers from the 28 KB-per-segment svec tables.
__global__ __launch_bounds__(256) void head_final(const float* __restrict__ svec,
                                                  const int* __restrict__ tpl,
                                                  const float* __restrict__ wv,
                                                  float* __restrict__ outp) {
    int m = blockIdx.x * 256 + threadIdx.x;
    if (m >= M_TPL) return;
    int d1 = tpl[3 * m + 0];
    int d2 = tpl[3 * m + 1];
    int se = tpl[3 * m + 2];
    float c0 = wv[384];
    outp[m] = hshrink(svec[d1] + svec[SVPAD + d2] + svec[2 * SVPAD + se] + c0);
}

// ---------------------------------------------------------------------------
extern "C" void kernel_launch(void* const* d_in, const int* in_sizes, int n_in,
                              void* d_out, int out_size, void* d_ws, size_t ws_size,
                              hipStream_t stream) {
    const float* drugF = (const float*)d_in[0];
    const float* A     = (const float*)d_in[1];
    const int*   tpl   = (const int*)d_in[2];
    const float* rsd   = (const float*)d_in[3];
    const float* W1    = (const float*)d_in[4];
    const float* b1    = (const float*)d_in[5];
    const float* W2    = (const float*)d_in[6];
    const float* b2    = (const float*)d_in[7];
    const float* embSe = (const float*)d_in[8];
    const float* Wl    = (const float*)d_in[9];
    const float* bl    = (const float*)d_in[10];
    const float* Wp1   = (const float*)d_in[11];
    const float* bp1   = (const float*)d_in[12];
    const float* Wp2   = (const float*)d_in[13];
    const float* bp2   = (const float*)d_in[14];
    float* outp = (float*)d_out;

    float* ws = (float*)d_ws;
    const size_t XSZ = (size_t)N_TOT * E_DIM;   // 896000 floats
    const size_t P_AX  = (size_t)SPL_AX * XSZ;
    const size_t P_MLP = (size_t)SPL_MLP * N_D * E_DIM;
    const size_t PARTS = P_AX > P_MLP ? P_AX : P_MLP;
    float* x     = ws;
    float* parts = ws + XSZ;
    u16* xT   = (u16*)(ws + XSZ + PARTS);
    u16* W1T  = xT + (size_t)128 * KPAD;
    float* wv   = (float*)(W1T + (size_t)128 * 1024);   // 385 floats (pad 512)
    float* svec = wv + 512;                              // 3 * SVPAD floats

    // 0) W1 -> bf16 transpose + head weight-vector precompute
    transpose_bf16<<<dim3(1024 / 64, 2), 256, 0, stream>>>(W1, W1T, F_SIZE, 1024);
    head_wvec<<<dim3(1), 256, 0, stream>>>(Wp1, Wp2, bp1, bp2, wv);
    // 1) MLP layer 1 (pipelined DMA split-K) + fused-reduce MLP layer 2
    gemm_dma<<<dim3((N_D + 63) / 64, SPL_MLP), 256, 0, stream>>>(
        drugF, F_SIZE, W1T, 1024, parts, N_D, F_SIZE);
    gemm_small2<<<dim3((N_D + 15) / 16), 256, 0, stream>>>(
        parts, SPL_MLP, (size_t)N_D * E_DIM, b1, W2, b2, x, N_D, 0);
    // 2) embSe rows
    emb_copy<<<dim3((N_SE * E_DIM / 4 + 255) / 256), 256, 0, stream>>>(embSe, x);
    // 3) two propagation layers: x = HS( (A@x) @ Wl[i] + bl[i] )
    for (int l = 0; l < 2; l++) {
        transpose_bf16<<<dim3(KPAD / 64, 2), 256, 0, stream>>>(x, xT, N_TOT, KPAD);
        gemm_dma<<<dim3((N_TOT + 63) / 64, SPL_AX), 256, 0, stream>>>(
            A, N_TOT, xT, KPAD, parts, N_TOT, N_TOT);
        gemm_small2<<<dim3((N_TOT + 15) / 16), 256, 0, stream>>>(
            parts, SPL_AX, XSZ, nullptr,
            Wl + (size_t)l * E_DIM * E_DIM, bl + (size_t)l * E_DIM, x, N_TOT, 1);
    }
    // 4) head: per-row scalar tables, then 3-gather + hardshrink
    head_svec<<<dim3((N_TOT + 63) / 64), 256, 0, stream>>>(x, rsd, wv, svec);
    head_final<<<dim3((M_TPL + 255) / 256), 256, 0, stream>>>(svec, tpl, wv, outp);
}